// Round 1
// baseline (712.792 us; speedup 1.0000x reference)
//
#include <hip/hip_runtime.h>
#include <math.h>

#define NMODES 32
#define NPAIR 496
#define TAYLOR_N 12

// T2 matrix in module-scope device memory (d_ws may be zero-sized).
__device__ float2 g_T2[NMODES * NMODES];

__device__ __forceinline__ float2 cmul(float2 a, float2 b) {
    return make_float2(a.x * b.x - a.y * b.y, a.x * b.y + a.y * b.x);
}

// ---------------------------------------------------------------------------
// Setup kernel: one block of 1024 threads builds T2 (32x32 complex).
//   H from params  ->  U = expm(iH) (scale & square + Taylor-Horner)
//   W = U^T U      ->  mix = (1.1 I - W)^{-1} W  (Gauss-Jordan, partial pivot)
//   T2[i][j] = -kappa_i * kappa_j * (0.5*delta_ij + mix[i][j])
// ---------------------------------------------------------------------------
__global__ __launch_bounds__(1024) void setup_kernel(const float* __restrict__ params,
                                                     const float* __restrict__ kappa) {
    __shared__ float2 X[NMODES][NMODES];
    __shared__ float2 R[NMODES][NMODES];
    __shared__ float2 W[NMODES][NMODES];
    __shared__ float2 Aug[NMODES][2 * NMODES];
    __shared__ int sh_s;
    __shared__ float sh_scale;
    __shared__ int sh_piv;
    __shared__ float2 sh_pivrec;

    const int tid = threadIdx.x;
    const int i = tid >> 5;
    const int j = tid & 31;

    // --- build H ---
    float2 h;
    if (i == j) {
        float d;
        if (i < 31) {
            d = params[2 * NPAIR + i];
        } else {
            d = 0.0f;
            for (int r = 0; r < 31; ++r) d -= params[2 * NPAIR + r];
        }
        h = make_float2(d, 0.0f);
    } else {
        int a = (i < j) ? i : j;
        int b = (i < j) ? j : i;
        int idx = 31 * a - (a * (a - 1)) / 2 + (b - a - 1);  // row-major triu
        float re = params[idx];
        float im = params[NPAIR + idx];
        h = (i < j) ? make_float2(re, im) : make_float2(re, -im);
    }
    X[i][j] = h;
    __syncthreads();

    // --- inf-norm (wave 0, parallel rows + shuffle max-reduce) ---
    if (tid < 32) {
        float s = 0.0f;
        for (int c = 0; c < NMODES; ++c) {
            float2 v = X[tid][c];
            s += sqrtf(v.x * v.x + v.y * v.y);
        }
        for (int off = 16; off > 0; off >>= 1)
            s = fmaxf(s, __shfl_down(s, off));
        if (tid == 0) {
            int sc_n = 0;
            float sc = 1.0f;
            while (s > 0.25f && sc_n < 40) { s *= 0.5f; sc *= 0.5f; ++sc_n; }
            sh_s = sc_n;
            sh_scale = sc;
        }
    }
    __syncthreads();

    // --- X = (i*H) * 2^{-s} ---
    {
        float sc = sh_scale;
        float2 v = X[i][j];
        X[i][j] = make_float2(-v.y * sc, v.x * sc);
    }
    __syncthreads();

    // --- Taylor via Horner: R = I; for k=N..1: R = I + (X*R)/k ---
    R[i][j] = make_float2((i == j) ? 1.0f : 0.0f, 0.0f);
    __syncthreads();
    for (int k = TAYLOR_N; k >= 1; --k) {
        float2 acc = make_float2(0.0f, 0.0f);
        for (int kk = 0; kk < NMODES; ++kk) {
            float2 a = X[i][kk];
            float2 b = R[kk][j];
            acc.x = fmaf(a.x, b.x, fmaf(-a.y, b.y, acc.x));
            acc.y = fmaf(a.x, b.y, fmaf(a.y, b.x, acc.y));
        }
        __syncthreads();
        float invk = 1.0f / (float)k;
        R[i][j] = make_float2(((i == j) ? 1.0f : 0.0f) + acc.x * invk, acc.y * invk);
        __syncthreads();
    }

    // --- squarings ---
    {
        int s = sh_s;
        for (int q = 0; q < s; ++q) {
            float2 acc = make_float2(0.0f, 0.0f);
            for (int kk = 0; kk < NMODES; ++kk) {
                float2 a = R[i][kk];
                float2 b = R[kk][j];
                acc.x = fmaf(a.x, b.x, fmaf(-a.y, b.y, acc.x));
                acc.y = fmaf(a.x, b.y, fmaf(a.y, b.x, acc.y));
            }
            __syncthreads();
            R[i][j] = acc;
            __syncthreads();
        }
    }

    // --- W = U^T U (no conjugation) ---
    {
        float2 acc = make_float2(0.0f, 0.0f);
        for (int kk = 0; kk < NMODES; ++kk) {
            float2 a = R[kk][i];
            float2 b = R[kk][j];
            acc.x = fmaf(a.x, b.x, fmaf(-a.y, b.y, acc.x));
            acc.y = fmaf(a.x, b.y, fmaf(a.y, b.x, acc.y));
        }
        W[i][j] = acc;
    }
    __syncthreads();

    // --- augmented [1.1 I - W | W] ---
    {
        float2 w = W[i][j];
        Aug[i][j] = make_float2(((i == j) ? 1.1f : 0.0f) - w.x, -w.y);
        Aug[i][j + NMODES] = w;
    }
    __syncthreads();

    // --- Gauss-Jordan with partial pivoting; right half -> mix ---
    for (int p = 0; p < NMODES; ++p) {
        if (tid < 32) {  // parallel argmax pivot search (wave 0)
            float2 v = Aug[tid][p];
            float mag = (tid >= p) ? (v.x * v.x + v.y * v.y) : -1.0f;
            int idx = tid;
            for (int off = 16; off > 0; off >>= 1) {
                float omg = __shfl_down(mag, off);
                int oi = __shfl_down(idx, off);
                if (omg > mag) { mag = omg; idx = oi; }
            }
            if (tid == 0) sh_piv = idx;
        }
        __syncthreads();
        int piv = sh_piv;
        if (piv != p && i == p) {
            float2 a0 = Aug[p][j], b0 = Aug[piv][j];
            float2 a1 = Aug[p][j + NMODES], b1 = Aug[piv][j + NMODES];
            Aug[p][j] = b0; Aug[piv][j] = a0;
            Aug[p][j + NMODES] = b1; Aug[piv][j + NMODES] = a1;
        }
        __syncthreads();
        if (tid == 0) {
            float2 d = Aug[p][p];
            float den = d.x * d.x + d.y * d.y;
            sh_pivrec = make_float2(d.x / den, -d.y / den);
        }
        __syncthreads();
        if (i == p) {
            float2 pr = sh_pivrec;
            Aug[p][j] = cmul(Aug[p][j], pr);
            Aug[p][j + NMODES] = cmul(Aug[p][j + NMODES], pr);
        }
        __syncthreads();
        float2 f = Aug[i][p];
        __syncthreads();
        if (i != p) {
            float2 rp0 = Aug[p][j];
            float2 rp1 = Aug[p][j + NMODES];
            float2 v0 = Aug[i][j];
            float2 v1 = Aug[i][j + NMODES];
            v0.x -= f.x * rp0.x - f.y * rp0.y;
            v0.y -= f.x * rp0.y + f.y * rp0.x;
            v1.x -= f.x * rp1.x - f.y * rp1.y;
            v1.y -= f.x * rp1.y + f.y * rp1.x;
            Aug[i][j] = v0;
            Aug[i][j + NMODES] = v1;
        }
        __syncthreads();
    }

    // --- T2 ---
    {
        float2 mix = Aug[i][j + NMODES];
        float kk2 = fabsf(kappa[i]) * fabsf(kappa[j]);
        float re = -kk2 * (((i == j) ? 0.5f : 0.0f) + mix.x);
        float im = -kk2 * mix.y;
        g_T2[i * NMODES + j] = make_float2(re, im);
    }
}

// ---------------------------------------------------------------------------
// Main ODE kernel, split-K x2: block = 64 threads = 1 wave = 1 batch.
// lane = (m = lane>>1, h = lane&1). Each lane holds half of T2 row m
// (k = h*16 .. h*16+15) and computes a half dot; halves combine via
// __shfl_xor(.,1).
//
// NEW (this round): the per-stage state broadcast is a STATIC permutation
// (mode k lives in lanes 2k / 2k+1), so the LDS write -> barrier -> b128-read
// round-trip (~212 exposed cyc/eval, the phase-locked-wave stall) is replaced
// by register-to-register ds_bpermute gathers: lane (m,h) pulls x[16h+j]
// from lane 2*(16h+j), i.e. byte index 128*h + 8*j (one index VGPR, the 8*j
// folds into the DS offset field). No LDS memory, no barrier, single DS
// latency per stage, pipelined against the FMA chain via counted lgkmcnt.
// ---------------------------------------------------------------------------
__device__ __forceinline__ void gather16(float2* __restrict__ xg, float2 v, int abase) {
#pragma unroll
    for (int j = 0; j < 16; ++j) {
        const int idx = abase + 8 * j;  // 4 * (32*h + 2*j): source lane holds mode 16h+j
        xg[j].x = __int_as_float(__builtin_amdgcn_ds_bpermute(idx, __float_as_int(v.x)));
        xg[j].y = __int_as_float(__builtin_amdgcn_ds_bpermute(idx, __float_as_int(v.y)));
    }
}

__device__ __forceinline__ float2 f_eval(const float2* __restrict__ xg,
                                         float2 ym,
                                         const float2* __restrict__ t2h,
                                         float om, float nl2) {
    float2 acc0 = make_float2(0.0f, 0.0f);
    float2 acc1 = make_float2(0.0f, 0.0f);
#pragma unroll
    for (int j = 0; j < 16; j += 2) {
        float2 va = xg[j];
        float2 vb = xg[j + 1];
        float2 ta = t2h[j];
        float2 tb = t2h[j + 1];
        acc0.x = fmaf(-ta.y, va.y, fmaf(ta.x, va.x, acc0.x));
        acc0.y = fmaf( ta.y, va.x, fmaf(ta.x, va.y, acc0.y));
        acc1.x = fmaf(-tb.y, vb.y, fmaf(tb.x, vb.x, acc1.x));
        acc1.y = fmaf( tb.y, vb.x, fmaf(tb.x, vb.y, acc1.y));
    }
    float ax = acc0.x + acc1.x;
    float ay = acc0.y + acc1.y;
    ax += __shfl_xor(ax, 1);  // combine K-halves; both lanes get full sum
    ay += __shfl_xor(ay, 1);
    float w = fmaf(nl2, fmaf(ym.x, ym.x, ym.y * ym.y), om);
    return make_float2(ax - w * ym.y, ay + w * ym.x);
}

__global__ __launch_bounds__(64) void ode_kernel(const float* __restrict__ A0r,
                                                 const float* __restrict__ A0i,
                                                 const float* __restrict__ omega,
                                                 const float* __restrict__ nln,
                                                 float* __restrict__ out,
                                                 long long out_size) {
    const int lane = threadIdx.x;
    const int m = lane >> 1;
    const int h = lane & 1;
    const int b = blockIdx.x;
    const int abase = 128 * h;

    // half T2 row: 16 complex = 32 VGPRs
    float2 t2h[16];
#pragma unroll
    for (int j = 0; j < 16; ++j) t2h[j] = g_T2[m * NMODES + h * 16 + j];

    const float om = omega[m];
    const float nl = nln[0];
    const float nl2 = nl * nl;
    const float dt = 1.0f / 199.0f;
    const float hdt = 0.5f * dt;
    const float sdt = dt / 6.0f;

    float2 a;
    if (m < 24) a = make_float2(A0r[b * 24 + m], A0i[b * 24 + m]);
    else        a = make_float2(1.0f, 0.0f);

    float2 xg[16];           // this lane's K-half of the current stage input
    gather16(xg, a, abase);  // t = 0 state

    long long o = (long long)b * 32 + m;
    if (h == 0 && o < out_size) out[o] = a.x;  // t = 0 output (real plane only)

    for (int t = 1; t < 200; ++t) {
        float2 k1 = f_eval(xg, a, t2h, om, nl2);
        float2 y = make_float2(fmaf(hdt, k1.x, a.x), fmaf(hdt, k1.y, a.y));
        gather16(xg, y, abase);

        float2 k2 = f_eval(xg, y, t2h, om, nl2);
        y = make_float2(fmaf(hdt, k2.x, a.x), fmaf(hdt, k2.y, a.y));
        gather16(xg, y, abase);

        float2 k3 = f_eval(xg, y, t2h, om, nl2);
        y = make_float2(fmaf(dt, k3.x, a.x), fmaf(dt, k3.y, a.y));
        gather16(xg, y, abase);

        float2 k4 = f_eval(xg, y, t2h, om, nl2);

        a.x = fmaf(sdt, fmaf(2.0f, k2.x + k3.x, k1.x + k4.x), a.x);
        a.y = fmaf(sdt, fmaf(2.0f, k2.y + k3.y, k1.y + k4.y), a.y);
        gather16(xg, a, abase);

        o += 65536;  // 2048 * 32
        if (h == 0 && o < out_size) out[o] = a.x;
    }
}

extern "C" void kernel_launch(void* const* d_in, const int* in_sizes, int n_in,
                              void* d_out, int out_size, void* d_ws, size_t ws_size,
                              hipStream_t stream) {
    const float* A0r = (const float*)d_in[0];
    const float* A0i = (const float*)d_in[1];
    const float* omega = (const float*)d_in[2];
    const float* kappa = (const float*)d_in[3];
    const float* nln = (const float*)d_in[4];
    const float* params = (const float*)d_in[5];

    setup_kernel<<<1, 1024, 0, stream>>>(params, kappa);
    ode_kernel<<<2048, 64, 0, stream>>>(A0r, A0i, omega, nln,
                                        (float*)d_out, (long long)out_size);
}

// Round 3
// 394.205 us; speedup vs baseline: 1.8082x; 1.8082x over previous
//
#include <hip/hip_runtime.h>
#include <math.h>

#define NMODES 32
#define NPAIR 496
#define TAYLOR_N 12

// T2 matrix in module-scope device memory (d_ws may be zero-sized).
__device__ float2 g_T2[NMODES * NMODES];

__device__ __forceinline__ float2 cmul(float2 a, float2 b) {
    return make_float2(a.x * b.x - a.y * b.y, a.x * b.y + a.y * b.x);
}

// ---------------------------------------------------------------------------
// Setup kernel: one block of 1024 threads builds T2 (32x32 complex).
//   H from params  ->  U = expm(iH) (scale & square + Taylor-Horner)
//   W = U^T U      ->  mix = (1.1 I - W)^{-1} W  (Gauss-Jordan, partial pivot)
//   T2[i][j] = -kappa_i * kappa_j * (0.5*delta_ij + mix[i][j])
// (unchanged from the round-0 PASSING kernel)
// ---------------------------------------------------------------------------
__global__ __launch_bounds__(1024) void setup_kernel(const float* __restrict__ params,
                                                     const float* __restrict__ kappa) {
    __shared__ float2 X[NMODES][NMODES];
    __shared__ float2 R[NMODES][NMODES];
    __shared__ float2 W[NMODES][NMODES];
    __shared__ float2 Aug[NMODES][2 * NMODES];
    __shared__ int sh_s;
    __shared__ float sh_scale;
    __shared__ int sh_piv;
    __shared__ float2 sh_pivrec;

    const int tid = threadIdx.x;
    const int i = tid >> 5;
    const int j = tid & 31;

    // --- build H ---
    float2 h;
    if (i == j) {
        float d;
        if (i < 31) {
            d = params[2 * NPAIR + i];
        } else {
            d = 0.0f;
            for (int r = 0; r < 31; ++r) d -= params[2 * NPAIR + r];
        }
        h = make_float2(d, 0.0f);
    } else {
        int a = (i < j) ? i : j;
        int b = (i < j) ? j : i;
        int idx = 31 * a - (a * (a - 1)) / 2 + (b - a - 1);  // row-major triu
        float re = params[idx];
        float im = params[NPAIR + idx];
        h = (i < j) ? make_float2(re, im) : make_float2(re, -im);
    }
    X[i][j] = h;
    __syncthreads();

    // --- inf-norm (wave 0, parallel rows + shuffle max-reduce) ---
    if (tid < 32) {
        float s = 0.0f;
        for (int c = 0; c < NMODES; ++c) {
            float2 v = X[tid][c];
            s += sqrtf(v.x * v.x + v.y * v.y);
        }
        for (int off = 16; off > 0; off >>= 1)
            s = fmaxf(s, __shfl_down(s, off));
        if (tid == 0) {
            int sc_n = 0;
            float sc = 1.0f;
            while (s > 0.25f && sc_n < 40) { s *= 0.5f; sc *= 0.5f; ++sc_n; }
            sh_s = sc_n;
            sh_scale = sc;
        }
    }
    __syncthreads();

    // --- X = (i*H) * 2^{-s} ---
    {
        float sc = sh_scale;
        float2 v = X[i][j];
        X[i][j] = make_float2(-v.y * sc, v.x * sc);
    }
    __syncthreads();

    // --- Taylor via Horner: R = I; for k=N..1: R = I + (X*R)/k ---
    R[i][j] = make_float2((i == j) ? 1.0f : 0.0f, 0.0f);
    __syncthreads();
    for (int k = TAYLOR_N; k >= 1; --k) {
        float2 acc = make_float2(0.0f, 0.0f);
        for (int kk = 0; kk < NMODES; ++kk) {
            float2 a = X[i][kk];
            float2 b = R[kk][j];
            acc.x = fmaf(a.x, b.x, fmaf(-a.y, b.y, acc.x));
            acc.y = fmaf(a.x, b.y, fmaf(a.y, b.x, acc.y));
        }
        __syncthreads();
        float invk = 1.0f / (float)k;
        R[i][j] = make_float2(((i == j) ? 1.0f : 0.0f) + acc.x * invk, acc.y * invk);
        __syncthreads();
    }

    // --- squarings ---
    {
        int s = sh_s;
        for (int q = 0; q < s; ++q) {
            float2 acc = make_float2(0.0f, 0.0f);
            for (int kk = 0; kk < NMODES; ++kk) {
                float2 a = R[i][kk];
                float2 b = R[kk][j];
                acc.x = fmaf(a.x, b.x, fmaf(-a.y, b.y, acc.x));
                acc.y = fmaf(a.x, b.y, fmaf(a.y, b.x, acc.y));
            }
            __syncthreads();
            R[i][j] = acc;
            __syncthreads();
        }
    }

    // --- W = U^T U (no conjugation) ---
    {
        float2 acc = make_float2(0.0f, 0.0f);
        for (int kk = 0; kk < NMODES; ++kk) {
            float2 a = R[kk][i];
            float2 b = R[kk][j];
            acc.x = fmaf(a.x, b.x, fmaf(-a.y, b.y, acc.x));
            acc.y = fmaf(a.x, b.y, fmaf(a.y, b.x, acc.y));
        }
        W[i][j] = acc;
    }
    __syncthreads();

    // --- augmented [1.1 I - W | W] ---
    {
        float2 w = W[i][j];
        Aug[i][j] = make_float2(((i == j) ? 1.1f : 0.0f) - w.x, -w.y);
        Aug[i][j + NMODES] = w;
    }
    __syncthreads();

    // --- Gauss-Jordan with partial pivoting; right half -> mix ---
    for (int p = 0; p < NMODES; ++p) {
        if (tid < 32) {  // parallel argmax pivot search (wave 0)
            float2 v = Aug[tid][p];
            float mag = (tid >= p) ? (v.x * v.x + v.y * v.y) : -1.0f;
            int idx = tid;
            for (int off = 16; off > 0; off >>= 1) {
                float omg = __shfl_down(mag, off);
                int oi = __shfl_down(idx, off);
                if (omg > mag) { mag = omg; idx = oi; }
            }
            if (tid == 0) sh_piv = idx;
        }
        __syncthreads();
        int piv = sh_piv;
        if (piv != p && i == p) {
            float2 a0 = Aug[p][j], b0 = Aug[piv][j];
            float2 a1 = Aug[p][j + NMODES], b1 = Aug[piv][j + NMODES];
            Aug[p][j] = b0; Aug[piv][j] = a0;
            Aug[p][j + NMODES] = b1; Aug[piv][j + NMODES] = a1;
        }
        __syncthreads();
        if (tid == 0) {
            float2 d = Aug[p][p];
            float den = d.x * d.x + d.y * d.y;
            sh_pivrec = make_float2(d.x / den, -d.y / den);
        }
        __syncthreads();
        if (i == p) {
            float2 pr = sh_pivrec;
            Aug[p][j] = cmul(Aug[p][j], pr);
            Aug[p][j + NMODES] = cmul(Aug[p][j + NMODES], pr);
        }
        __syncthreads();
        float2 f = Aug[i][p];
        __syncthreads();
        if (i != p) {
            float2 rp0 = Aug[p][j];
            float2 rp1 = Aug[p][j + NMODES];
            float2 v0 = Aug[i][j];
            float2 v1 = Aug[i][j + NMODES];
            v0.x -= f.x * rp0.x - f.y * rp0.y;
            v0.y -= f.x * rp0.y + f.y * rp0.x;
            v1.x -= f.x * rp1.x - f.y * rp1.y;
            v1.y -= f.x * rp1.y + f.y * rp1.x;
            Aug[i][j] = v0;
            Aug[i][j + NMODES] = v1;
        }
        __syncthreads();
    }

    // --- T2 ---
    {
        float2 mix = Aug[i][j + NMODES];
        float kk2 = fabsf(kappa[i]) * fabsf(kappa[j]);
        float re = -kk2 * (((i == j) ? 0.5f : 0.0f) + mix.x);
        float im = -kk2 * mix.y;
        g_T2[i * NMODES + j] = make_float2(re, im);
    }
}

// ---------------------------------------------------------------------------
// Main ODE kernel — systolic XOR-ring v2, 1 wave = 1 batch item.
//
// Round-0/1 counters proved the LDS-staged structure LDS-pipe-bound
// (8 waves/CU x ~102 DS-cyc/eval = 812 cyc/eval = measured wall). This
// version keeps the state in registers and circulates it on the VALU pipe.
//
// T2 as 16x16 blocks [A B; C D] over the wave's four 16-lane rows:
//   row0 (lanes  0-15): holds u=y[0:16],  computes A*u  (partial of out-lo)
//   row1 (lanes 16-31): holds v=y[16:32], computes D*v  (partial of out-hi)
//   row2 (lanes 32-47): holds v,          computes B*v  (partial of out-lo)
//   row3 (lanes 48-63): holds u,          computes C*u  (partial of out-hi)
// Each lane owns ONE mode (mstar) and holds the Gray-ordered block diagonal
// t2[s] = T2[16*ho+p][16*hr+(p^e_s)], e_s = {0,1,3,2,5,4,6,7,8,9,11,10,13,12,14,15}.
// Ring transitions use ONLY mirror-family DPP (involutions, no direction
// conventions, no DS): xor1/xor2 -> quad_perm, xor7 -> row_half_mirror,
// xor15 -> row_mirror.
// Combine: each lane gathers its two needed block-partials directly via
// ds_bpermute (proven across all 64 lanes in round 1) at 4*mstar and
// 4*mstar+128 — replaces round-2's permlane asm (suspected same-register
// coalescing bug: tied "+v" operands from one SSA value -> swap-with-self).
// ---------------------------------------------------------------------------
template<int CTRL>
__device__ __forceinline__ float2 dppshuf(float2 v) {
    return make_float2(
        __int_as_float(__builtin_amdgcn_mov_dpp(__float_as_int(v.x), CTRL, 0xF, 0xF, true)),
        __int_as_float(__builtin_amdgcn_mov_dpp(__float_as_int(v.y), CTRL, 0xF, 0xF, true)));
}

#define QP_X1 0xB1   // quad_perm [1,0,3,2]   == xor 1
#define QP_X2 0x4E   // quad_perm [2,3,0,1]   == xor 2
#define HM_X7 0x141  // row_half_mirror       == xor 7  (within 8)
#define RM_XF 0x140  // row_mirror            == xor 15 (within 16)

__device__ __forceinline__ void cfma(float2& acc, float2 c, float2 w) {
    acc.x = fmaf(c.x, w.x, fmaf(-c.y, w.y, acc.x));
    acc.y = fmaf(c.x, w.y, fmaf(c.y, w.x, acc.y));
}

__device__ __forceinline__ float bperm(int idx, float v) {
    return __int_as_float(__builtin_amdgcn_ds_bpermute(idx, __float_as_int(v)));
}

__device__ __forceinline__ float2 feval(const float2* __restrict__ t2,
                                        float2 z, float om, float nl2,
                                        int bp0, int bp1) {
    float2 pa = make_float2(0.0f, 0.0f);
    float2 pb = make_float2(0.0f, 0.0f);
    float2 w = z;
    cfma(pa, t2[0],  w);  w = dppshuf<QP_X1>(w);   // e 0 -> 1
    cfma(pb, t2[1],  w);  w = dppshuf<QP_X2>(w);   // 1 -> 3
    cfma(pa, t2[2],  w);  w = dppshuf<QP_X1>(w);   // 3 -> 2
    cfma(pb, t2[3],  w);  w = dppshuf<HM_X7>(w);   // 2 -> 5
    cfma(pa, t2[4],  w);  w = dppshuf<QP_X1>(w);   // 5 -> 4
    cfma(pb, t2[5],  w);  w = dppshuf<QP_X2>(w);   // 4 -> 6
    cfma(pa, t2[6],  w);  w = dppshuf<QP_X1>(w);   // 6 -> 7
    cfma(pb, t2[7],  w);  w = dppshuf<RM_XF>(w);   // 7 -> 8
    cfma(pa, t2[8],  w);  w = dppshuf<QP_X1>(w);   // 8 -> 9
    cfma(pb, t2[9],  w);  w = dppshuf<QP_X2>(w);   // 9 -> 11
    cfma(pa, t2[10], w);  w = dppshuf<QP_X1>(w);   // 11 -> 10
    cfma(pb, t2[11], w);  w = dppshuf<HM_X7>(w);   // 10 -> 13
    cfma(pa, t2[12], w);  w = dppshuf<QP_X1>(w);   // 13 -> 12
    cfma(pb, t2[13], w);  w = dppshuf<QP_X2>(w);   // 12 -> 14
    cfma(pa, t2[14], w);  w = dppshuf<QP_X1>(w);   // 14 -> 15
    cfma(pb, t2[15], w);

    float px = pa.x + pb.x;
    float py = pa.y + pb.y;
    // Each lane gathers the two partials of ITS owned output row directly:
    // partial(out-lo[p]) lives in lanes p and 32+p; partial(out-hi[p]) in
    // lanes 16+p and 48+p. bp0 = 4*mstar, bp1 = bp0 + 128.
    float kx = bperm(bp0, px) + bperm(bp1, px);
    float ky = bperm(bp0, py) + bperm(bp1, py);

    // local nonlinear/frequency term for the held mode
    float wf = fmaf(nl2, fmaf(z.x, z.x, z.y * z.y), om);
    return make_float2(kx - wf * z.y, ky + wf * z.x);
}

__global__ __launch_bounds__(64) void ode_kernel(const float* __restrict__ A0r,
                                                 const float* __restrict__ A0i,
                                                 const float* __restrict__ omega,
                                                 const float* __restrict__ nln,
                                                 float* __restrict__ out,
                                                 long long out_size) {
    const int lane = threadIdx.x;
    const int r = lane >> 4;
    const int p = lane & 15;
    const int ho = r & 1;                       // output half this row computes
    const int hr = (r == 1 || r == 2) ? 1 : 0;  // held (ring) half
    const int mstar = 16 * hr + p;              // mode this lane owns
    const int bp0 = 4 * mstar;                  // bpermute: first partial
    const int bp1 = bp0 + 128;                  // bpermute: second partial
    const int b = blockIdx.x;

    // T2 block diagonal for this lane (Gray-code column order)
    float2 t2[16];
    {
        const int row_g = 16 * ho + p;
        constexpr int ecol[16] = {0, 1, 3, 2, 5, 4, 6, 7, 8, 9, 11, 10, 13, 12, 14, 15};
#pragma unroll
        for (int s = 0; s < 16; ++s)
            t2[s] = g_T2[row_g * 32 + 16 * hr + (p ^ ecol[s])];
    }

    const float om = omega[mstar];
    const float nl = nln[0];
    const float nl2 = nl * nl;
    const float dt = 1.0f / 199.0f;
    const float hdt = 0.5f * dt;
    const float sdt = dt / 6.0f;

    // initial state for the held mode (one LDS bounce; lane l<32 owns mode l)
    __shared__ float2 ainit[32];
    if (lane < 32) {
        float2 v;
        if (lane < 24) v = make_float2(A0r[b * 24 + lane], A0i[b * 24 + lane]);
        else           v = make_float2(1.0f, 0.0f);
        ainit[lane] = v;
    }
    __syncthreads();
    float2 a = ainit[mstar];

    // t = 0 output (real plane only, guarded); lane l < 32 holds mode l
    long long o = (long long)b * 32 + lane;
    if (lane < 32 && o < out_size) out[o] = a.x;

    for (int t = 1; t < 200; ++t) {
        float2 k1 = feval(t2, a, om, nl2, bp0, bp1);
        float2 z = make_float2(fmaf(hdt, k1.x, a.x), fmaf(hdt, k1.y, a.y));
        float2 k2 = feval(t2, z, om, nl2, bp0, bp1);
        z = make_float2(fmaf(hdt, k2.x, a.x), fmaf(hdt, k2.y, a.y));
        float2 k3 = feval(t2, z, om, nl2, bp0, bp1);
        z = make_float2(fmaf(dt, k3.x, a.x), fmaf(dt, k3.y, a.y));
        float2 k4 = feval(t2, z, om, nl2, bp0, bp1);

        a.x = fmaf(sdt, fmaf(2.0f, k2.x + k3.x, k1.x + k4.x), a.x);
        a.y = fmaf(sdt, fmaf(2.0f, k2.y + k3.y, k1.y + k4.y), a.y);

        o += 65536;  // 2048 * 32
        if (lane < 32 && o < out_size) out[o] = a.x;
    }
}

extern "C" void kernel_launch(void* const* d_in, const int* in_sizes, int n_in,
                              void* d_out, int out_size, void* d_ws, size_t ws_size,
                              hipStream_t stream) {
    const float* A0r = (const float*)d_in[0];
    const float* A0i = (const float*)d_in[1];
    const float* omega = (const float*)d_in[2];
    const float* kappa = (const float*)d_in[3];
    const float* nln = (const float*)d_in[4];
    const float* params = (const float*)d_in[5];

    setup_kernel<<<1, 1024, 0, stream>>>(params, kappa);
    ode_kernel<<<2048, 64, 0, stream>>>(A0r, A0i, omega, nln,
                                        (float*)d_out, (long long)out_size);
}